// Round 11
// baseline (1110.448 us; speedup 1.0000x reference)
//
#include <hip/hip_runtime.h>
#include <hip/hip_cooperative_groups.h>
#include <math.h>

namespace cg = cooperative_groups;

#define NN 100000      // nodes
#define CD 32          // classes / hidden
#define NPB 4          // waves per block
#define G_NPW 2        // nodes per wave in gathers (R23-proven; R25's 4 was neutral)

#define B1N ((NN + 255) >> 8)   // 391 coarse buckets (256 nodes each)
#define EPB_A 2048              // edges per partition block (256 thr x 8)

typedef unsigned int   uint32;
typedef unsigned short ushort16;

// fp32 -> bf16 round-to-nearest-even
__device__ __forceinline__ ushort16 f2b(float f) {
    uint32 u = __float_as_uint(f);
    u = (u + 0x7FFFu + ((u >> 16) & 1u)) >> 16;
    return (ushort16)u;
}
__device__ __forceinline__ float b2f_lo(uint32 u) { return __uint_as_float(u << 16); }
__device__ __forceinline__ float b2f_hi(uint32 u) { return __uint_as_float(u & 0xFFFF0000u); }

// R22: order-preserving bf16->u16 key space; gather max = one v_pk_max_u16.
__device__ __forceinline__ uint32 pkmax(uint32 a, uint32 b) {
    uint32 d;
    asm("v_pk_max_u16 %0, %1, %2" : "=v"(d) : "v"(a), "v"(b));
    return d;
}
__device__ __forceinline__ uint32 key16(float f) {
    uint32 b = (uint32)f2b(f);
    return b ^ ((__float_as_uint(f) >> 31) ? 0xFFFFu : 0x8000u);
}
__device__ __forceinline__ uint32 dec_pk(uint32 k) {
    uint32 m = (~k >> 15) & 0x00010001u;
    uint32 X = 0x80008000u | ((m << 15) - m);
    return k ^ X;
}

__device__ __forceinline__ int edge_is64(const void* edge) {
    const long long* p = (const long long*)edge;
    int lane = threadIdx.x & 63;
    int bad = 0;
    for (int i = lane; i < 512; i += 64) {
        long long v = p[i];
        if (v < 0 || v >= NN) bad = 1;
    }
    unsigned long long anybad = __ballot(bad);
    return (anybad == 0ULL) ? 1 : 0;
}

__device__ __forceinline__ int load_idx(const void* edge, int i, int is64) {
    if (is64) return (int)((const long long*)edge)[i];
    return ((const int*)edge)[i];
}

// ---------------------------------------------------------------------------
// R26: ONE cooperative mega-kernel. ~120 us of the R23 total was serialized
// dispatch-boundary overhead (13 launches x ~8-10 us); phases are separated
// by grid.sync() (~2-4 us each) instead. Bodies are the R23-proven kernels,
// grid-strided; LDS reused across virtual blocks with trailing barriers.

struct MegaArgs {
    const float* x;
    const void*  edge;
    int E, nblkA, cvtb, gb, db;
    const float *Wl1, *bl1, *Wr1, *Wl2, *bl2, *Wr2, *Wl3, *bl3, *Wr3;
    uint32* xb; int* hist; int* binTotal; int* offsets; int* csr_src;
    const uint32* bucketed_r; uint32* bucketed_w;
    uint32* agg1; uint32* h1b; uint32* agg2; uint32* h2b; uint32* agg3;
    float* outf;
};

// ---- gather bodies (R21/R23-proven permuted shfl-broadcast structure) ----
__device__ __forceinline__ void g50_window(uint32* a_, int sidx, int mm,
                                           const char* hbase, uint32 joff,
                                           int p, int lb) {
    int k = p;
    for (; k + 14 < mm; k += 16) {
        const int kh = lb + (k >> 1);
#pragma unroll
        for (int kk = 0; kk < 8; ++kk) {
            int s = __shfl(sidx, kh + kk);
            uint32 u = *(const uint32*)(hbase + ((((uint32)s) << 7) | joff));
            a_[kk] = pkmax(a_[kk], u);
        }
    }
    for (; k + 6 < mm; k += 8) {
        const int kh = lb + (k >> 1);
#pragma unroll
        for (int kk = 0; kk < 4; ++kk) {
            int s = __shfl(sidx, kh + kk);
            uint32 u = *(const uint32*)(hbase + ((((uint32)s) << 7) | joff));
            a_[kk] = pkmax(a_[kk], u);
        }
    }
    for (; k < mm; k += 2) {
        int s = __shfl(sidx, lb + (k >> 1));
        uint32 u = *(const uint32*)(hbase + ((((uint32)s) << 7) | joff));
        a_[0] = pkmax(a_[0], u);
    }
}

__device__ __forceinline__ void gather50_body(int vb, const uint32* hb,
                                              const int* offsets,
                                              const int* csr_src,
                                              uint32* aggB) {
    const int tid  = threadIdx.x;
    const int g    = tid >> 6;
    const int lane = tid & 63;
    const int p    = lane >> 5;
    const int j    = lane & 31;
    const int n0   = (vb * NPB + g) * 2;
    if (n0 >= NN) return;                  // wave-uniform; no barriers below
    const int n1   = n0 + 1;
    const bool has1 = (n1 < NN);

    const int beg0 = offsets[n0];
    const int end0 = offsets[n0 + 1];
    const int beg1 = has1 ? offsets[n1] : 0;
    const int end1 = has1 ? offsets[n1 + 1] : 0;
    const char* hbase = (const char*)hb;
    const uint32 joff = (uint32)(j << 2);
    const int lb = p << 5;
    const int myidx = 2 * j + p;

    uint32 a_[8], b_[8];
#pragma unroll
    for (int k = 0; k < 8; ++k) { a_[k] = 0; b_[k] = 0; }

    const int d0 = end0 - beg0, d1 = end1 - beg1;
    const int mm0 = d0 < 64 ? d0 : 64;
    const int mm1 = d1 < 64 ? d1 : 64;
    int sidx0 = 0, sidx1 = 0;
    if (myidx < mm0) sidx0 = csr_src[beg0 + myidx];
    if (myidx < mm1) sidx1 = csr_src[beg1 + myidx];
    g50_window(a_, sidx0, mm0, hbase, joff, p, lb);
    g50_window(b_, sidx1, mm1, hbase, joff, p, lb);
    for (int ib = beg0 + 64; ib < end0; ib += 64) {
        const int rem = end0 - ib;
        const int mm = rem < 64 ? rem : 64;
        int s = (myidx < mm) ? csr_src[ib + myidx] : 0;
        g50_window(a_, s, mm, hbase, joff, p, lb);
    }
    for (int ib = beg1 + 64; ib < end1; ib += 64) {
        const int rem = end1 - ib;
        const int mm = rem < 64 ? rem : 64;
        int s = (myidx < mm) ? csr_src[ib + myidx] : 0;
        g50_window(b_, s, mm, hbase, joff, p, lb);
    }
#pragma unroll
    for (int off2 = 4; off2 > 0; off2 >>= 1)
#pragma unroll
        for (int k = 0; k < off2; ++k) {
            a_[k] = pkmax(a_[k], a_[k + off2]);
            b_[k] = pkmax(b_[k], b_[k + off2]);
        }
    uint32 r0 = a_[0], r1 = b_[0];
    r0 = pkmax(r0, (uint32)__shfl_xor((int)r0, 32));
    r1 = pkmax(r1, (uint32)__shfl_xor((int)r1, 32));
    if (p == 0 && j < 25) {
        aggB[(size_t)n0 * 32 + j] = (beg0 == end0) ? 0x80008000u : r0;
        if (has1)
            aggB[(size_t)n1 * 32 + j] = (beg1 == end1) ? 0x80008000u : r1;
    }
}

__device__ __forceinline__ void g32_window(uint32* a_, int sidx, int mm,
                                           const char* hbase, uint32 coff,
                                           int e, int lb) {
    int k = e;
    for (; k + 12 < mm; k += 16) {
        const int m = lb + (k >> 2);
        int s0 = __shfl(sidx, m);
        int s1 = __shfl(sidx, m + 1);
        int s2 = __shfl(sidx, m + 2);
        int s3 = __shfl(sidx, m + 3);
        uint32 u0 = *(const uint32*)(hbase + ((((uint32)s0) << 6) | coff));
        uint32 u1 = *(const uint32*)(hbase + ((((uint32)s1) << 6) | coff));
        uint32 u2 = *(const uint32*)(hbase + ((((uint32)s2) << 6) | coff));
        uint32 u3 = *(const uint32*)(hbase + ((((uint32)s3) << 6) | coff));
        a_[0] = pkmax(a_[0], u0); a_[1] = pkmax(a_[1], u1);
        a_[2] = pkmax(a_[2], u2); a_[3] = pkmax(a_[3], u3);
    }
    for (; k < mm; k += 4) {
        int s = __shfl(sidx, lb + (k >> 2));
        uint32 u = *(const uint32*)(hbase + ((((uint32)s) << 6) | coff));
        a_[0] = pkmax(a_[0], u);
    }
}

__device__ __forceinline__ void gather32_body(int vb, const uint32* hb,
                                              const int* offsets,
                                              const int* csr_src,
                                              uint32* aggB) {
    const int tid  = threadIdx.x;
    const int g    = tid >> 6;
    const int lane = tid & 63;
    const int e    = lane >> 4;
    const int c    = lane & 15;
    const int n0   = (vb * NPB + g) * 2;
    if (n0 >= NN) return;
    const int n1   = n0 + 1;
    const bool has1 = (n1 < NN);

    const int beg0 = offsets[n0];
    const int end0 = offsets[n0 + 1];
    const int beg1 = has1 ? offsets[n1] : 0;
    const int end1 = has1 ? offsets[n1 + 1] : 0;
    const char* hbase = (const char*)hb;
    const uint32 coff = (uint32)(c << 2);
    const int lb = e << 4;
    const int myidx = 4 * c + e;

    uint32 a_[4] = {0, 0, 0, 0};
    uint32 b_[4] = {0, 0, 0, 0};

    const int d0 = end0 - beg0, d1 = end1 - beg1;
    const int mm0 = d0 < 64 ? d0 : 64;
    const int mm1 = d1 < 64 ? d1 : 64;
    int sidx0 = 0, sidx1 = 0;
    if (myidx < mm0) sidx0 = csr_src[beg0 + myidx];
    if (myidx < mm1) sidx1 = csr_src[beg1 + myidx];
    g32_window(a_, sidx0, mm0, hbase, coff, e, lb);
    g32_window(b_, sidx1, mm1, hbase, coff, e, lb);
    for (int ib = beg0 + 64; ib < end0; ib += 64) {
        const int rem = end0 - ib;
        const int mm = rem < 64 ? rem : 64;
        int s = (myidx < mm) ? csr_src[ib + myidx] : 0;
        g32_window(a_, s, mm, hbase, coff, e, lb);
    }
    for (int ib = beg1 + 64; ib < end1; ib += 64) {
        const int rem = end1 - ib;
        const int mm = rem < 64 ? rem : 64;
        int s = (myidx < mm) ? csr_src[ib + myidx] : 0;
        g32_window(b_, s, mm, hbase, coff, e, lb);
    }

    uint32 r0 = pkmax(pkmax(a_[0], a_[1]), pkmax(a_[2], a_[3]));
    uint32 r1 = pkmax(pkmax(b_[0], b_[1]), pkmax(b_[2], b_[3]));
    r0 = pkmax(r0, (uint32)__shfl_xor((int)r0, 16));
    r0 = pkmax(r0, (uint32)__shfl_xor((int)r0, 32));
    r1 = pkmax(r1, (uint32)__shfl_xor((int)r1, 16));
    r1 = pkmax(r1, (uint32)__shfl_xor((int)r1, 32));
    if (lane < 16) {
        aggB[(size_t)n0 * 16 + lane] = (beg0 == end0) ? 0x80008000u : r0;
        if (has1)
            aggB[(size_t)n1 * 16 + lane] = (beg1 == end1) ? 0x80008000u : r1;
    }
}

// ---- dense body (R11-proven lane-per-node; wave-uniform W -> s_load) ----
template <int DIN, int ASTR, int HSTR, int OSTR, int MODE>
__device__ __forceinline__ void dense_body(int vb, const uint32* aggB,
                                           const uint32* hB,
                                           const float* Wl, const float* bl,
                                           const float* Wr, void* out_v) {
    const int n = vb * 256 + threadIdx.x;
    if (n >= NN) return;

    float acc[CD];
#pragma unroll
    for (int j = 0; j < CD; ++j) acc[j] = bl[j];

    {
        const uint32* row = aggB + (size_t)n * ASTR;
        for (int c = 0; c < DIN / 4; ++c) {
            uint2 u = *(const uint2*)&row[c * 2];
            u.x = dec_pk(u.x); u.y = dec_pk(u.y);
            float d0 = b2f_lo(u.x), d1 = b2f_hi(u.x);
            float d2 = b2f_lo(u.y), d3 = b2f_hi(u.y);
            const float* w = Wl + c * 4 * CD;
#pragma unroll
            for (int j = 0; j < CD; ++j)
                acc[j] += d0 * w[j] + d1 * w[CD + j] + d2 * w[2 * CD + j] + d3 * w[3 * CD + j];
        }
        if (DIN % 4) {
            uint32 u = dec_pk(row[(DIN / 4) * 2]);
            float d0 = b2f_lo(u), d1 = b2f_hi(u);
            const float* w = Wl + (DIN - 2) * CD;
#pragma unroll
            for (int j = 0; j < CD; ++j)
                acc[j] += d0 * w[j] + d1 * w[CD + j];
        }
    }
    {
        const uint32* row = hB + (size_t)n * HSTR;
        for (int c = 0; c < DIN / 4; ++c) {
            uint2 u = *(const uint2*)&row[c * 2];
            u.x = dec_pk(u.x); u.y = dec_pk(u.y);
            float d0 = b2f_lo(u.x), d1 = b2f_hi(u.x);
            float d2 = b2f_lo(u.y), d3 = b2f_hi(u.y);
            const float* w = Wr + c * 4 * CD;
#pragma unroll
            for (int j = 0; j < CD; ++j)
                acc[j] += d0 * w[j] + d1 * w[CD + j] + d2 * w[2 * CD + j] + d3 * w[3 * CD + j];
        }
        if (DIN % 4) {
            uint32 u = dec_pk(row[(DIN / 4) * 2]);
            float d0 = b2f_lo(u), d1 = b2f_hi(u);
            const float* w = Wr + (DIN - 2) * CD;
#pragma unroll
            for (int j = 0; j < CD; ++j)
                acc[j] += d0 * w[j] + d1 * w[CD + j];
        }
    }

    if (MODE == 0) {
        uint32* orow = (uint32*)out_v + (size_t)n * OSTR;
#pragma unroll
        for (int c = 0; c < CD / 2; ++c) {
            float a0 = fmaxf(acc[2 * c],     0.0f);
            float a1 = fmaxf(acc[2 * c + 1], 0.0f);
            orow[c] = ((uint32)f2b(a0) | ((uint32)f2b(a1) << 16)) | 0x80008000u;
        }
    } else {
        float m = acc[0];
#pragma unroll
        for (int j = 1; j < CD; ++j) m = fmaxf(m, acc[j]);
        float s = 0.0f;
#pragma unroll
        for (int j = 0; j < CD; ++j) s += expf(acc[j] - m);
        const float lse = m + logf(s);
        float* orow = (float*)out_v + (size_t)n * CD;
#pragma unroll
        for (int j = 0; j < CD; ++j) orow[j] = acc[j] - lse;
    }
}

// ---------------------------------------------------------------------------
__global__ void mega_kernel(MegaArgs A) {
    cg::grid_group grid = cg::this_grid();
    const int NB  = gridDim.x;
    const int bid = blockIdx.x;
    const int t   = threadIdx.x;

    __shared__ int lh[B1N];
    __shared__ int ts[256];
    __shared__ int lbase[B1N + 1];
    __shared__ int hh[256];
    __shared__ int sc[256];
    __shared__ int cur[B1N];

    const int is64 = edge_is64(A.edge);

    // ---- P0: cvt (key-encode x) + per-block histogram of dst>>8 ----------
    for (int vb = bid; vb < A.nblkA + A.cvtb; vb += NB) {
        if (vb < A.nblkA) {
            for (int b = t; b < B1N; b += 256) lh[b] = 0;
            __syncthreads();
            const int e0 = vb * EPB_A + t;
#pragma unroll
            for (int k = 0; k < 8; ++k) {
                int e = e0 + k * 256;
                if (e < A.E) {
                    int d = load_idx(A.edge, A.E + e, is64);
                    atomicAdd(&lh[d >> 8], 1);
                }
            }
            __syncthreads();
            int* gh = A.hist + (size_t)vb * B1N;
            for (int b = t; b < B1N; b += 256) gh[b] = lh[b];
            __syncthreads();           // lh reused next virtual block
        } else {
            const int tt = (vb - A.nblkA) * 256 + t;
            if (tt < NN * 32) {
                const int n = tt >> 5;
                const int c = tt & 31;
                if (c >= 25) A.xb[tt] = 0;
                else {
                    float2 v = *(const float2*)&A.x[n * 50 + 2 * c];
                    A.xb[tt] = key16(v.x) | (key16(v.y) << 16);
                }
            }
        }
    }
    grid.sync();

    // ---- P1: per-bin exclusive scan of hist over blocks ------------------
    for (int vb = bid; vb < B1N; vb += NB) {
        const int bin = vb;
        const int base = t * 4;
        int v0 = (base + 0 < A.nblkA) ? A.hist[(size_t)(base + 0) * B1N + bin] : 0;
        int v1 = (base + 1 < A.nblkA) ? A.hist[(size_t)(base + 1) * B1N + bin] : 0;
        int v2 = (base + 2 < A.nblkA) ? A.hist[(size_t)(base + 2) * B1N + bin] : 0;
        int v3 = (base + 3 < A.nblkA) ? A.hist[(size_t)(base + 3) * B1N + bin] : 0;
        const int s = v0 + v1 + v2 + v3;
        ts[t] = s;
        __syncthreads();
        for (int off = 1; off < 256; off <<= 1) {
            int u = (t >= off) ? ts[t - off] : 0;
            __syncthreads();
            ts[t] += u;
            __syncthreads();
        }
        int e = ts[t] - s;
        if (base + 0 < A.nblkA) { A.hist[(size_t)(base + 0) * B1N + bin] = e; e += v0; }
        if (base + 1 < A.nblkA) { A.hist[(size_t)(base + 1) * B1N + bin] = e; e += v1; }
        if (base + 2 < A.nblkA) { A.hist[(size_t)(base + 2) * B1N + bin] = e; e += v2; }
        if (base + 3 < A.nblkA) { A.hist[(size_t)(base + 3) * B1N + bin] = e; e += v3; }
        if (t == 255) A.binTotal[bin] = ts[255];
        __syncthreads();
    }
    grid.sync();

    // helper: in-block exclusive scan of binTotal -> lbase (per block, once)
    auto scan_bins = [&]() {
        const int base = t * 2;
        const int v0 = (base + 0 < B1N) ? A.binTotal[base + 0] : 0;
        const int v1 = (base + 1 < B1N) ? A.binTotal[base + 1] : 0;
        const int s = v0 + v1;
        ts[t] = s;
        __syncthreads();
        for (int off = 1; off < 256; off <<= 1) {
            int u = (t >= off) ? ts[t - off] : 0;
            __syncthreads();
            ts[t] += u;
            __syncthreads();
        }
        const int e = ts[t] - s;
        if (base + 0 < B1N) lbase[base + 0] = e;
        if (base + 1 < B1N) lbase[base + 1] = e + v0;
        if (t == 255) lbase[B1N] = ts[255];
        __syncthreads();
    };

    // ---- P2: scatter into coarse buckets (LDS cursors) -------------------
    scan_bins();
    for (int vb = bid; vb < A.nblkA; vb += NB) {
        const int* gh = A.hist + (size_t)vb * B1N;
        for (int b = t; b < B1N; b += 256) cur[b] = lbase[b] + gh[b];
        __syncthreads();
        const int e0 = vb * EPB_A + t;
#pragma unroll
        for (int k = 0; k < 8; ++k) {
            int e = e0 + k * 256;
            if (e < A.E) {
                int s = load_idx(A.edge, e, is64);
                int d = load_idx(A.edge, A.E + e, is64);
                int pos = atomicAdd(&cur[d >> 8], 1);
                A.bucketed_w[pos] = (uint32)s | ((uint32)(d & 255) << 17);
            }
        }
        __syncthreads();               // cur reused next virtual block
    }
    grid.sync();

    // ---- P3: per-bucket finalize -> offsets + csr_src --------------------
    for (int vb = bid; vb < B1N; vb += NB) {
        const int start = lbase[vb];
        const int end   = lbase[vb + 1];
        hh[t] = 0;
        __syncthreads();
        for (int i = start + t; i < end; i += 256)
            atomicAdd(&hh[A.bucketed_r[i] >> 17], 1);
        __syncthreads();
        const int v = hh[t];
        sc[t] = v;
        __syncthreads();
        for (int off = 1; off < 256; off <<= 1) {
            int u = (t >= off) ? sc[t - off] : 0;
            __syncthreads();
            sc[t] += u;
            __syncthreads();
        }
        const int excl = sc[t] - v;
        const int node = vb * 256 + t;
        if (node < NN) A.offsets[node] = start + excl;
        cur[t] = start + excl;
        __syncthreads();
        for (int i = start + t; i < end; i += 256) {
            uint32 p = A.bucketed_r[i];
            int pos = atomicAdd(&cur[p >> 17], 1);
            A.csr_src[pos] = (int)(p & 0x1FFFFu);
        }
        if (vb == B1N - 1 && t == 0) A.offsets[NN] = end;
        __syncthreads();
    }
    grid.sync();

    // ---- P4: gather50 ----------------------------------------------------
    for (int vb = bid; vb < A.gb; vb += NB)
        gather50_body(vb, A.xb, A.offsets, A.csr_src, A.agg1);
    grid.sync();

    // ---- P5: dense L1 (50 -> 32, relu) -----------------------------------
    for (int vb = bid; vb < A.db; vb += NB)
        dense_body<50, 32, 32, 16, 0>(vb, A.agg1, A.xb, A.Wl1, A.bl1, A.Wr1, A.h1b);
    grid.sync();

    // ---- P6: gather32 L2 -------------------------------------------------
    for (int vb = bid; vb < A.gb; vb += NB)
        gather32_body(vb, A.h1b, A.offsets, A.csr_src, A.agg2);
    grid.sync();

    // ---- P7: dense L2 (32 -> 32, relu) -----------------------------------
    for (int vb = bid; vb < A.db; vb += NB)
        dense_body<32, 16, 16, 16, 0>(vb, A.agg2, A.h1b, A.Wl2, A.bl2, A.Wr2, A.h2b);
    grid.sync();

    // ---- P8: gather32 L3 -------------------------------------------------
    for (int vb = bid; vb < A.gb; vb += NB)
        gather32_body(vb, A.h2b, A.offsets, A.csr_src, A.agg3);
    grid.sync();

    // ---- P9: dense L3 (32 -> 32, log_softmax -> fp32) --------------------
    for (int vb = bid; vb < A.db; vb += NB)
        dense_body<32, 16, 16, 0, 2>(vb, A.agg3, A.h2b, A.Wl3, A.bl3, A.Wr3, A.outf);
}

// ---------------------------------------------------------------------------
extern "C" void kernel_launch(void* const* d_in, const int* in_sizes, int n_in,
                              void* d_out, int out_size, void* d_ws, size_t ws_size,
                              hipStream_t stream) {
    const float* x    = (const float*)d_in[0];
    const void*  edge = d_in[1];

    const int E = in_sizes[1] / 2;

    // Workspace carve-up (256B aligned), ~26 MB (R23 layout). bucketed+hist
    // in d_out (dead before agg1 in P4); h2b reuses xb (dead after P5);
    // agg3 reuses h1b (dead after P7).
    char* ws = (char*)d_ws;
    size_t off = 0;
    auto carve = [&](size_t bytes) {
        void* p = ws + off;
        off = (off + bytes + 255) & ~(size_t)255;
        return p;
    };
    int*    offsets   = (int*)   carve((size_t)(NN + 1) * 4);
    int*    binTotal  = (int*)   carve((size_t)B1N * 4);
    int*    csr_src   = (int*)   carve((size_t)E * 4);
    uint32* xb        = (uint32*)carve((size_t)NN * 32 * 4);  // 12.8 MB
    uint32* h1b       = (uint32*)carve((size_t)NN * 16 * 4);  // 6.4 MB
    (void)ws_size; (void)n_in; (void)out_size;

    uint32* bucketed = (uint32*)d_out;
    int*    hist     = (int*)((char*)d_out + (((size_t)E * 4 + 255) & ~(size_t)255));

    MegaArgs a;
    a.x = x; a.edge = edge; a.E = E;
    a.nblkA = (E + EPB_A - 1) / EPB_A;
    a.cvtb  = (NN * 32 + 255) / 256;
    a.gb    = (NN + NPB * G_NPW - 1) / (NPB * G_NPW);
    a.db    = (NN + 255) / 256;
    a.Wl1 = (const float*)d_in[2];  a.bl1 = (const float*)d_in[3];
    a.Wr1 = (const float*)d_in[4];
    a.Wl2 = (const float*)d_in[5];  a.bl2 = (const float*)d_in[6];
    a.Wr2 = (const float*)d_in[7];
    a.Wl3 = (const float*)d_in[8];  a.bl3 = (const float*)d_in[9];
    a.Wr3 = (const float*)d_in[10];
    a.xb = xb; a.hist = hist; a.binTotal = binTotal;
    a.offsets = offsets; a.csr_src = csr_src;
    a.bucketed_r = bucketed; a.bucketed_w = bucketed;
    a.agg1 = (uint32*)d_out;                  // stride 32, 12.8 MB
    a.h1b  = h1b;
    a.agg2 = (uint32*)d_out;                  // stride 16, 6.4 MB
    a.h2b  = xb;                              // xb dead after P5
    a.agg3 = h1b;                             // h1b dead after P7
    a.outf = (float*)d_out;

    // Co-resident grid size (occupancy-bounded; cooperative launch requires
    // all blocks resident for grid.sync).
    static int gridBlocks = 0;
    if (gridBlocks == 0) {
        int nb = 0;
        hipOccupancyMaxActiveBlocksPerMultiprocessor(&nb, (const void*)mega_kernel, 256, 0);
        if (nb < 1) nb = 1;
        gridBlocks = nb * 256;                // 256 CUs on MI355X
        if (gridBlocks > 2048) gridBlocks = 2048;
    }

    void* kargs[] = { &a };
    hipLaunchCooperativeKernel((const void*)mega_kernel, dim3(gridBlocks),
                               dim3(256), kargs, 0, stream);
}

// Round 12
// 288.372 us; speedup vs baseline: 3.8508x; 3.8508x over previous
//
#include <hip/hip_runtime.h>
#include <math.h>

#define NN 100000      // nodes
#define CD 32          // classes / hidden
#define NPB 4          // waves per block in gather kernels (2 nodes per wave)

#define B1N ((NN + 255) >> 8)   // 391 coarse buckets (256 nodes each)
#define EPB_A 2048              // edges per partition block (256 thr x 8)

// R26 POST-MORTEM (do not retry): fusing all phases into one cooperative
// kernel with grid.sync() ran 1485 us — grid.sync at ~1500 blocks costs
// ~100+ us/sync on gfx950 (VALUBusy 4.5% = barrier spin). Dispatch
// boundaries under graph capture are far cheaper than grid syncs.
// R24 (feature-blocked 3-pass gather): 3x latency rounds/node, 68 us. NO.
// R25 (4 nodes/wave): neutral-to-negative vs 2. Keep 2.

typedef unsigned int   uint32;
typedef unsigned short ushort16;

// fp32 -> bf16 round-to-nearest-even
__device__ __forceinline__ ushort16 f2b(float f) {
    uint32 u = __float_as_uint(f);
    u = (u + 0x7FFFu + ((u >> 16) & 1u)) >> 16;
    return (ushort16)u;
}
// packed bf16 pair -> two fp32 (exact)
__device__ __forceinline__ float b2f_lo(uint32 u) { return __uint_as_float(u << 16); }
__device__ __forceinline__ float b2f_hi(uint32 u) { return __uint_as_float(u & 0xFFFF0000u); }

// ---------------------------------------------------------------------------
// R22: order-preserving bf16->u16 key space (max-of-keys == key-of-max);
// per-uint gather max = ONE v_pk_max_u16.
__device__ __forceinline__ uint32 pkmax(uint32 a, uint32 b) {
    uint32 d;
    asm("v_pk_max_u16 %0, %1, %2" : "=v"(d) : "v"(a), "v"(b));
    return d;
}
// fp32 -> bf16 key (scalar)
__device__ __forceinline__ uint32 key16(float f) {
    uint32 b = (uint32)f2b(f);
    return b ^ ((__float_as_uint(f) >> 31) ? 0xFFFFu : 0x8000u);
}
// packed key pair -> packed bf16 pair (general sign)
__device__ __forceinline__ uint32 dec_pk(uint32 k) {
    uint32 m = (~k >> 15) & 0x00010001u;            // 1 where original < 0
    uint32 X = 0x80008000u | ((m << 15) - m);       // per half: neg?0xFFFF:0x8000
    return k ^ X;
}

// Inline is64 detection (R17).
__device__ __forceinline__ int edge_is64(const void* edge) {
    const long long* p = (const long long*)edge;
    int lane = threadIdx.x & 63;
    int bad = 0;
    for (int i = lane; i < 512; i += 64) {
        long long v = p[i];
        if (v < 0 || v >= NN) bad = 1;
    }
    unsigned long long anybad = __ballot(bad);
    return (anybad == 0ULL) ? 1 : 0;
}

__device__ __forceinline__ int load_idx(const void* edge, int i, int is64) {
    if (is64) return (int)((const long long*)edge)[i];
    return ((const int*)edge)[i];
}

// ---------------------------------------------------------------------------
// Fused cvt + hist (R22). Monolithic stride-32 xb (128-B aligned rows).
__global__ __launch_bounds__(256) void cvt_hist_kernel(const float* __restrict__ x,
                                                       uint32* __restrict__ xb,
                                                       const void* edge, int E,
                                                       int* __restrict__ hist,
                                                       int nblkA) {
    __shared__ int lh[B1N];
    const int t = threadIdx.x;
    if ((int)blockIdx.x < nblkA) {
        const int is64 = edge_is64(edge);
        for (int b = t; b < B1N; b += 256) lh[b] = 0;
        __syncthreads();
        const int e0 = blockIdx.x * EPB_A + t;
#pragma unroll
        for (int k = 0; k < 8; ++k) {
            int e = e0 + k * 256;
            if (e < E) {
                int d = load_idx(edge, E + e, is64);
                atomicAdd(&lh[d >> 8], 1);
            }
        }
        __syncthreads();
        int* gh = hist + (size_t)blockIdx.x * B1N;
        for (int b = t; b < B1N; b += 256) gh[b] = lh[b];
    } else {
        const int tt = (blockIdx.x - nblkA) * 256 + t;
        if (tt >= NN * 32) return;
        const int n = tt >> 5;
        const int c = tt & 31;
        if (c >= 25) { xb[tt] = 0; return; }
        float2 v = *(const float2*)&x[n * 50 + 2 * c];
        xb[tt] = key16(v.x) | (key16(v.y) << 16);
    }
}

// One block per bin: exclusive scan of hist[b][bin] over blocks b (in place),
// bin total to binTotal[bin]. Supports nblk <= 1024 (4 per thread).
__global__ __launch_bounds__(256) void scanA_kernel(int* __restrict__ hist,
                                                    int nblk,
                                                    int* __restrict__ binTotal) {
    __shared__ int ts[256];
    const int bin = blockIdx.x;
    const int t = threadIdx.x;
    const int base = t * 4;
    int v0 = (base + 0 < nblk) ? hist[(size_t)(base + 0) * B1N + bin] : 0;
    int v1 = (base + 1 < nblk) ? hist[(size_t)(base + 1) * B1N + bin] : 0;
    int v2 = (base + 2 < nblk) ? hist[(size_t)(base + 2) * B1N + bin] : 0;
    int v3 = (base + 3 < nblk) ? hist[(size_t)(base + 3) * B1N + bin] : 0;
    const int s = v0 + v1 + v2 + v3;
    ts[t] = s;
    __syncthreads();
    for (int off = 1; off < 256; off <<= 1) {
        int u = (t >= off) ? ts[t - off] : 0;
        __syncthreads();
        ts[t] += u;
        __syncthreads();
    }
    int e = ts[t] - s;
    if (base + 0 < nblk) { hist[(size_t)(base + 0) * B1N + bin] = e; e += v0; }
    if (base + 1 < nblk) { hist[(size_t)(base + 1) * B1N + bin] = e; e += v1; }
    if (base + 2 < nblk) { hist[(size_t)(base + 2) * B1N + bin] = e; e += v2; }
    if (base + 3 < nblk) { hist[(size_t)(base + 3) * B1N + bin] = e; e += v3; }
    if (t == 255) binTotal[bin] = ts[255];
}

// In-block exclusive scan of binTotal[B1N] -> lbase[B1N+1] (LDS).
__device__ __forceinline__ void scan_bins_lds(const int* __restrict__ binTotal,
                                              int* ts, int* lbase) {
    const int t = threadIdx.x;
    const int base = t * 2;
    const int v0 = (base + 0 < B1N) ? binTotal[base + 0] : 0;
    const int v1 = (base + 1 < B1N) ? binTotal[base + 1] : 0;
    const int s = v0 + v1;
    ts[t] = s;
    __syncthreads();
    for (int off = 1; off < 256; off <<= 1) {
        int u = (t >= off) ? ts[t - off] : 0;
        __syncthreads();
        ts[t] += u;
        __syncthreads();
    }
    const int e = ts[t] - s;
    if (base + 0 < B1N) lbase[base + 0] = e;
    if (base + 1 < B1N) lbase[base + 1] = e + v0;
    if (t == 255) lbase[B1N] = ts[255];     // == E
    __syncthreads();
}

__global__ __launch_bounds__(256) void scatter_kernel(const void* edge, int E,
                                                      const int* __restrict__ hist,
                                                      const int* __restrict__ binTotal,
                                                      uint32* __restrict__ bucketed) {
    __shared__ int ts[256];
    __shared__ int lbase[B1N + 1];
    __shared__ int cur[B1N];
    const int is64 = edge_is64(edge);
    const int t = threadIdx.x;
    scan_bins_lds(binTotal, ts, lbase);
    const int* gh = hist + (size_t)blockIdx.x * B1N;
    for (int b = t; b < B1N; b += 256) cur[b] = lbase[b] + gh[b];
    __syncthreads();
    const int e0 = blockIdx.x * EPB_A + t;
#pragma unroll
    for (int k = 0; k < 8; ++k) {
        int e = e0 + k * 256;
        if (e < E) {
            int s = load_idx(edge, e, is64);
            int d = load_idx(edge, E + e, is64);
            int pos = atomicAdd(&cur[d >> 8], 1);   // LDS atomic
            bucketed[pos] = (uint32)s | ((uint32)(d & 255) << 17);
        }
    }
}

__global__ __launch_bounds__(256) void bucket_kernel(const uint32* __restrict__ bucketed,
                                                     const int* __restrict__ binTotal,
                                                     int* __restrict__ offsets,
                                                     int* __restrict__ csr_src) {
    __shared__ int ts[256];
    __shared__ int lbase[B1N + 1];
    __shared__ int h[256];
    __shared__ int sc[256];
    __shared__ int cur[256];
    const int bkt = blockIdx.x;
    const int t = threadIdx.x;
    scan_bins_lds(binTotal, ts, lbase);
    const int start = lbase[bkt];
    const int end   = lbase[bkt + 1];
    h[t] = 0;
    __syncthreads();
    for (int i = start + t; i < end; i += 256)
        atomicAdd(&h[bucketed[i] >> 17], 1);        // LDS atomic
    __syncthreads();
    const int v = h[t];
    sc[t] = v;
    __syncthreads();
    for (int off = 1; off < 256; off <<= 1) {
        int u = (t >= off) ? sc[t - off] : 0;
        __syncthreads();
        sc[t] += u;
        __syncthreads();
    }
    const int excl = sc[t] - v;
    const int node = bkt * 256 + t;
    if (node < NN) offsets[node] = start + excl;    // coalesced
    cur[t] = start + excl;
    __syncthreads();
    for (int i = start + t; i < end; i += 256) {
        uint32 p = bucketed[i];
        int pos = atomicAdd(&cur[p >> 17], 1);      // LDS atomic
        csr_src[pos] = (int)(p & 0x1FFFFu);         // L2-local scatter (16KB window)
    }
    if (bkt == B1N - 1 && t == 0) offsets[NN] = end;   // == E
}

// ---------------------------------------------------------------------------
// Gather-max kernels, key space. R23: TWO nodes per wave, software-pipelined
// (both index-window loads issue before any row round). R21 permuted window
// layout keeps shfl sources inside the executing sub-group.

__device__ __forceinline__ void g50_window(uint32* a_, int sidx, int mm,
                                           const char* hbase, uint32 joff,
                                           int p, int lb) {
    int k = p;
    for (; k + 14 < mm; k += 16) {
        const int kh = lb + (k >> 1);
#pragma unroll
        for (int kk = 0; kk < 8; ++kk) {
            int s = __shfl(sidx, kh + kk);     // intra-half source (R21 layout)
            uint32 u = *(const uint32*)(hbase + ((((uint32)s) << 7) | joff));
            a_[kk] = pkmax(a_[kk], u);
        }
    }
    for (; k + 6 < mm; k += 8) {
        const int kh = lb + (k >> 1);
#pragma unroll
        for (int kk = 0; kk < 4; ++kk) {
            int s = __shfl(sidx, kh + kk);
            uint32 u = *(const uint32*)(hbase + ((((uint32)s) << 7) | joff));
            a_[kk] = pkmax(a_[kk], u);
        }
    }
    for (; k < mm; k += 2) {
        int s = __shfl(sidx, lb + (k >> 1));
        uint32 u = *(const uint32*)(hbase + ((((uint32)s) << 7) | joff));
        a_[0] = pkmax(a_[0], u);
    }
}

__global__ void gather50_kernel(const uint32* __restrict__ hb,
                                const int* __restrict__ offsets,
                                const int* __restrict__ csr_src,
                                uint32* __restrict__ aggB) {
    const int tid  = threadIdx.x;
    const int g    = tid >> 6;
    const int lane = tid & 63;
    const int p    = lane >> 5;        // half-wave: edge parity
    const int j    = lane & 31;        // uint chunk
    const int n0   = (blockIdx.x * NPB + g) * 2;
    if (n0 >= NN) return;
    const int n1   = n0 + 1;
    const bool has1 = (n1 < NN);

    const int beg0 = offsets[n0];
    const int end0 = offsets[n0 + 1];
    const int beg1 = end0;                         // offsets[n1] == offsets[n0+1]
    const int end1 = has1 ? offsets[n1 + 1] : end0;
    const char* hbase = (const char*)hb;
    const uint32 joff = (uint32)(j << 2);
    const int lb = p << 5;             // this half's lane base
    const int myidx = 2 * j + p;       // R21 permuted window layout

    uint32 a_[8], b_[8];
#pragma unroll
    for (int k = 0; k < 8; ++k) { a_[k] = 0; b_[k] = 0; }

    // First windows of both nodes: issue BOTH index loads before any rows.
    const int d0 = end0 - beg0, d1 = end1 - beg1;
    const int mm0 = d0 < 64 ? d0 : 64;
    const int mm1 = d1 < 64 ? d1 : 64;
    int sidx0 = 0, sidx1 = 0;
    if (myidx < mm0) sidx0 = csr_src[beg0 + myidx];
    if (myidx < mm1) sidx1 = csr_src[beg1 + myidx];
    g50_window(a_, sidx0, mm0, hbase, joff, p, lb);
    g50_window(b_, sidx1, mm1, hbase, joff, p, lb);
    // Rare extra windows (degree > 64)
    for (int ib = beg0 + 64; ib < end0; ib += 64) {
        const int rem = end0 - ib;
        const int mm = rem < 64 ? rem : 64;
        int s = (myidx < mm) ? csr_src[ib + myidx] : 0;
        g50_window(a_, s, mm, hbase, joff, p, lb);
    }
    for (int ib = beg1 + 64; ib < end1; ib += 64) {
        const int rem = end1 - ib;
        const int mm = rem < 64 ? rem : 64;
        int s = (myidx < mm) ? csr_src[ib + myidx] : 0;
        g50_window(b_, s, mm, hbase, joff, p, lb);
    }

#pragma unroll
    for (int off2 = 4; off2 > 0; off2 >>= 1)
#pragma unroll
        for (int k = 0; k < off2; ++k) {
            a_[k] = pkmax(a_[k], a_[k + off2]);
            b_[k] = pkmax(b_[k], b_[k + off2]);
        }
    uint32 r0 = a_[0], r1 = b_[0];
    r0 = pkmax(r0, (uint32)__shfl_xor((int)r0, 32));   // combine parity halves
    r1 = pkmax(r1, (uint32)__shfl_xor((int)r1, 32));
    if (p == 0 && j < 25) {
        aggB[(size_t)n0 * 32 + j] = (beg0 == end0) ? 0x80008000u : r0;
        if (has1)
            aggB[(size_t)n1 * 32 + j] = (beg1 == end1) ? 0x80008000u : r1;
    }
}

__device__ __forceinline__ void g32_window(uint32* a_, int sidx, int mm,
                                           const char* hbase, uint32 coff,
                                           int e, int lb) {
    int k = e;
    for (; k + 12 < mm; k += 16) {
        const int m = lb + (k >> 2);
        int s0 = __shfl(sidx, m);              // intra-quarter sources
        int s1 = __shfl(sidx, m + 1);
        int s2 = __shfl(sidx, m + 2);
        int s3 = __shfl(sidx, m + 3);
        uint32 u0 = *(const uint32*)(hbase + ((((uint32)s0) << 6) | coff));
        uint32 u1 = *(const uint32*)(hbase + ((((uint32)s1) << 6) | coff));
        uint32 u2 = *(const uint32*)(hbase + ((((uint32)s2) << 6) | coff));
        uint32 u3 = *(const uint32*)(hbase + ((((uint32)s3) << 6) | coff));
        a_[0] = pkmax(a_[0], u0); a_[1] = pkmax(a_[1], u1);
        a_[2] = pkmax(a_[2], u2); a_[3] = pkmax(a_[3], u3);
    }
    for (; k < mm; k += 4) {
        int s = __shfl(sidx, lb + (k >> 2));
        uint32 u = *(const uint32*)(hbase + ((((uint32)s) << 6) | coff));
        a_[0] = pkmax(a_[0], u);
    }
}

__global__ void gather32_kernel(const uint32* __restrict__ hb,
                                const int* __restrict__ offsets,
                                const int* __restrict__ csr_src,
                                uint32* __restrict__ aggB) {
    const int tid  = threadIdx.x;
    const int g    = tid >> 6;
    const int lane = tid & 63;
    const int e    = lane >> 4;        // quarter-wave: edge slot mod 4
    const int c    = lane & 15;        // uint chunk
    const int n0   = (blockIdx.x * NPB + g) * 2;
    if (n0 >= NN) return;
    const int n1   = n0 + 1;
    const bool has1 = (n1 < NN);

    const int beg0 = offsets[n0];
    const int end0 = offsets[n0 + 1];
    const int beg1 = end0;                         // offsets[n1] == offsets[n0+1]
    const int end1 = has1 ? offsets[n1 + 1] : end0;
    const char* hbase = (const char*)hb;
    const uint32 coff = (uint32)(c << 2);
    const int lb = e << 4;             // this quarter's lane base
    const int myidx = 4 * c + e;       // R21 permuted window layout

    uint32 a_[4] = {0, 0, 0, 0};
    uint32 b_[4] = {0, 0, 0, 0};

    const int d0 = end0 - beg0, d1 = end1 - beg1;
    const int mm0 = d0 < 64 ? d0 : 64;
    const int mm1 = d1 < 64 ? d1 : 64;
    int sidx0 = 0, sidx1 = 0;
    if (myidx < mm0) sidx0 = csr_src[beg0 + myidx];
    if (myidx < mm1) sidx1 = csr_src[beg1 + myidx];
    g32_window(a_, sidx0, mm0, hbase, coff, e, lb);
    g32_window(b_, sidx1, mm1, hbase, coff, e, lb);
    for (int ib = beg0 + 64; ib < end0; ib += 64) {
        const int rem = end0 - ib;
        const int mm = rem < 64 ? rem : 64;
        int s = (myidx < mm) ? csr_src[ib + myidx] : 0;
        g32_window(a_, s, mm, hbase, coff, e, lb);
    }
    for (int ib = beg1 + 64; ib < end1; ib += 64) {
        const int rem = end1 - ib;
        const int mm = rem < 64 ? rem : 64;
        int s = (myidx < mm) ? csr_src[ib + myidx] : 0;
        g32_window(b_, s, mm, hbase, coff, e, lb);
    }

    uint32 r0 = pkmax(pkmax(a_[0], a_[1]), pkmax(a_[2], a_[3]));
    uint32 r1 = pkmax(pkmax(b_[0], b_[1]), pkmax(b_[2], b_[3]));
    r0 = pkmax(r0, (uint32)__shfl_xor((int)r0, 16));   // combine edge slots
    r0 = pkmax(r0, (uint32)__shfl_xor((int)r0, 32));
    r1 = pkmax(r1, (uint32)__shfl_xor((int)r1, 16));
    r1 = pkmax(r1, (uint32)__shfl_xor((int)r1, 32));
    if (lane < 16) {
        aggB[(size_t)n0 * 16 + lane] = (beg0 == end0) ? 0x80008000u : r0;
        if (has1)
            aggB[(size_t)n1 * 16 + lane] = (beg1 == end1) ? 0x80008000u : r1;
    }
}

// ---------------------------------------------------------------------------
// Dense kernel (R11-proven): one lane per node; 32 fp32 accumulators; wave-
// uniform weight addresses scalarize to s_load. Inputs key-encoded (dec_pk
// on load); MODE 0 stores relu output as keys (relu >= 0 -> OR 0x80008000);
// MODE 2 = log_softmax -> fp32.
template <int DIN, int ASTR, int HSTR, int OSTR, int MODE>
__global__ void dense_kernel(const uint32* __restrict__ aggB,
                             const uint32* __restrict__ hB,
                             const float* __restrict__ Wl,
                             const float* __restrict__ bl,
                             const float* __restrict__ Wr,
                             void* __restrict__ out_v) {
    const int n = blockIdx.x * blockDim.x + threadIdx.x;
    if (n >= NN) return;

    float acc[CD];
#pragma unroll
    for (int j = 0; j < CD; ++j) acc[j] = bl[j];

    {
        const uint32* row = aggB + (size_t)n * ASTR;
        for (int c = 0; c < DIN / 4; ++c) {
            uint2 u = *(const uint2*)&row[c * 2];
            u.x = dec_pk(u.x); u.y = dec_pk(u.y);
            float d0 = b2f_lo(u.x), d1 = b2f_hi(u.x);
            float d2 = b2f_lo(u.y), d3 = b2f_hi(u.y);
            const float* w = Wl + c * 4 * CD;
#pragma unroll
            for (int j = 0; j < CD; ++j)
                acc[j] += d0 * w[j] + d1 * w[CD + j] + d2 * w[2 * CD + j] + d3 * w[3 * CD + j];
        }
        if (DIN % 4) {
            uint32 u = dec_pk(row[(DIN / 4) * 2]);
            float d0 = b2f_lo(u), d1 = b2f_hi(u);
            const float* w = Wl + (DIN - 2) * CD;
#pragma unroll
            for (int j = 0; j < CD; ++j)
                acc[j] += d0 * w[j] + d1 * w[CD + j];
        }
    }
    {
        const uint32* row = hB + (size_t)n * HSTR;
        for (int c = 0; c < DIN / 4; ++c) {
            uint2 u = *(const uint2*)&row[c * 2];
            u.x = dec_pk(u.x); u.y = dec_pk(u.y);
            float d0 = b2f_lo(u.x), d1 = b2f_hi(u.x);
            float d2 = b2f_lo(u.y), d3 = b2f_hi(u.y);
            const float* w = Wr + c * 4 * CD;
#pragma unroll
            for (int j = 0; j < CD; ++j)
                acc[j] += d0 * w[j] + d1 * w[CD + j] + d2 * w[2 * CD + j] + d3 * w[3 * CD + j];
        }
        if (DIN % 4) {
            uint32 u = dec_pk(row[(DIN / 4) * 2]);
            float d0 = b2f_lo(u), d1 = b2f_hi(u);
            const float* w = Wr + (DIN - 2) * CD;
#pragma unroll
            for (int j = 0; j < CD; ++j)
                acc[j] += d0 * w[j] + d1 * w[CD + j];
        }
    }

    if (MODE == 0) {
        uint32* orow = (uint32*)out_v + (size_t)n * OSTR;
#pragma unroll
        for (int c = 0; c < CD / 2; ++c) {
            float a0 = fmaxf(acc[2 * c],     0.0f);
            float a1 = fmaxf(acc[2 * c + 1], 0.0f);
            // relu output >= 0 -> key encode is just setting the top bit
            orow[c] = ((uint32)f2b(a0) | ((uint32)f2b(a1) << 16)) | 0x80008000u;
        }
    } else {
        float m = acc[0];
#pragma unroll
        for (int j = 1; j < CD; ++j) m = fmaxf(m, acc[j]);
        float s = 0.0f;
#pragma unroll
        for (int j = 0; j < CD; ++j) s += expf(acc[j] - m);
        const float lse = m + logf(s);
        float* orow = (float*)out_v + (size_t)n * CD;
#pragma unroll
        for (int j = 0; j < CD; ++j) orow[j] = acc[j] - lse;
    }
}

// ---------------------------------------------------------------------------
extern "C" void kernel_launch(void* const* d_in, const int* in_sizes, int n_in,
                              void* d_out, int out_size, void* d_ws, size_t ws_size,
                              hipStream_t stream) {
    const float* x    = (const float*)d_in[0];
    const void*  edge = d_in[1];
    const float* Wl1 = (const float*)d_in[2];
    const float* bl1 = (const float*)d_in[3];
    const float* Wr1 = (const float*)d_in[4];
    const float* Wl2 = (const float*)d_in[5];
    const float* bl2 = (const float*)d_in[6];
    const float* Wr2 = (const float*)d_in[7];
    const float* Wl3 = (const float*)d_in[8];
    const float* bl3 = (const float*)d_in[9];
    const float* Wr3 = (const float*)d_in[10];

    const int E = in_sizes[1] / 2;

    // Workspace carve-up (256B aligned), ~26 MB. bucketed + hist live in
    // d_out (dead before agg1 is written there); h2b reuses xb (dead after
    // dense-L1); agg3 reuses h1b (dead after dense-L2).
    char* ws = (char*)d_ws;
    size_t off = 0;
    auto carve = [&](size_t bytes) {
        void* p = ws + off;
        off = (off + bytes + 255) & ~(size_t)255;
        return p;
    };
    int*    offsets   = (int*)   carve((size_t)(NN + 1) * 4);
    int*    binTotal  = (int*)   carve((size_t)B1N * 4);
    int*    csr_src   = (int*)   carve((size_t)E * 4);
    uint32* xb        = (uint32*)carve((size_t)NN * 32 * 4);  // 12.8 MB
    uint32* h1b       = (uint32*)carve((size_t)NN * 16 * 4);  // 6.4 MB
    (void)ws_size; (void)n_in; (void)out_size;

    uint32* bucketed = (uint32*)d_out;     // 6.4 MB, dead before agg1
    int*    hist     = (int*)((char*)d_out + (((size_t)E * 4 + 255) & ~(size_t)255));
    uint32* agg1 = (uint32*)d_out;         // L1 agg, stride 32 (12.8 MB = d_out)
    uint32* agg2 = (uint32*)d_out;         // L2 agg, stride 16
    uint32* h2b  = xb;                     // xb dead after dense-L1
    uint32* agg3 = h1b;                    // h1b dead after dense-L2

    // CSR build, LDS-atomic bucketing; cvt fused into the hist dispatch.
    const int nblkA = (E + EPB_A - 1) / EPB_A;     // 782 for E=1.6M
    const int cvtb  = (NN * 32 + 255) / 256;       // 12500
    cvt_hist_kernel<<<nblkA + cvtb, 256, 0, stream>>>(x, xb, edge, E, hist, nblkA);
    scanA_kernel<<<B1N, 256, 0, stream>>>(hist, nblkA, binTotal);
    scatter_kernel<<<nblkA, 256, 0, stream>>>(edge, E, hist, binTotal, bucketed);
    bucket_kernel<<<B1N, 256, 0, stream>>>(bucketed, binTotal, offsets, csr_src);

    const int gb = (NN + NPB * 2 - 1) / (NPB * 2);   // 2 nodes per wave
    const int db = (NN + 255) / 256;                 // lane per node

    // Layer 1: 50 -> 32, relu
    gather50_kernel<<<gb, 256, 0, stream>>>(xb, offsets, csr_src, agg1);
    dense_kernel<50, 32, 32, 16, 0><<<db, 256, 0, stream>>>(agg1, xb, Wl1, bl1, Wr1, h1b);
    // Layer 2: 32 -> 32, relu
    gather32_kernel<<<gb, 256, 0, stream>>>(h1b, offsets, csr_src, agg2);
    dense_kernel<32, 16, 16, 16, 0><<<db, 256, 0, stream>>>(agg2, h1b, Wl2, bl2, Wr2, h2b);
    // Layer 3: 32 -> 32, log_softmax -> fp32 d_out
    gather32_kernel<<<gb, 256, 0, stream>>>(h2b, offsets, csr_src, agg3);
    dense_kernel<32, 16, 16, 0, 2><<<db, 256, 0, stream>>>(agg3, h2b, Wl3, bl3, Wr3, d_out);
}